// Round 2
// baseline (519.037 us; speedup 1.0000x reference)
//
#include <hip/hip_runtime.h>
#include <hip/hip_bf16.h>

// B=4, T=2048, C=1024, H=16, HD=64. JOINED_DIM=25 (mask col%25==24 -> masked).

typedef __attribute__((ext_vector_type(8))) short short8;
typedef __attribute__((ext_vector_type(4))) float floatx4;

__device__ __forceinline__ unsigned short f2bf(float f){
    union { __hip_bfloat16 h; unsigned short u; } cv;
    cv.h = __float2bfloat16(f);
    return cv.u;
}

// async global->LDS, 16B per lane. LDS dest = wave-uniform base + lane*16.
__device__ __forceinline__ void ld_g2l16(const void* g, void* l){
    __builtin_amdgcn_global_load_lds((const __attribute__((address_space(1))) void*)g,
                                     (__attribute__((address_space(3))) void*)l, 16, 0, 0);
}

// ---------------- fp32 -> bf16 conversion ----------------
__global__ __launch_bounds__(256) void cvt_kernel(const float* __restrict__ in,
                                                  unsigned short* __restrict__ out, int n4){
    int i = blockIdx.x * 256 + threadIdx.x;
    if (i < n4){
        float4 v = reinterpret_cast<const float4*>(in)[i];
        ushort4 o;
        o.x = f2bf(v.x); o.y = f2bf(v.y); o.z = f2bf(v.z); o.w = f2bf(v.w);
        reinterpret_cast<ushort4*>(out)[i] = o;
    }
}

// 4 weight matrices (1024x1024 each) in one launch: 1024 blocks per weight.
__global__ __launch_bounds__(256) void cvt4_kernel(const float* __restrict__ w0, const float* __restrict__ w1,
                                                   const float* __restrict__ w2, const float* __restrict__ w3,
                                                   unsigned short* __restrict__ o0, unsigned short* __restrict__ o1,
                                                   unsigned short* __restrict__ o2, unsigned short* __restrict__ o3){
    int wsel = blockIdx.x >> 10;
    int i = (blockIdx.x & 1023) * 256 + threadIdx.x;
    const float* src = (wsel == 0) ? w0 : (wsel == 1) ? w1 : (wsel == 2) ? w2 : w3;
    unsigned short* dst = (wsel == 0) ? o0 : (wsel == 1) ? o1 : (wsel == 2) ? o2 : o3;
    float4 v = reinterpret_cast<const float4*>(src)[i];
    ushort4 o;
    o.x = f2bf(v.x); o.y = f2bf(v.y); o.z = f2bf(v.z); o.w = f2bf(v.w);
    reinterpret_cast<ushort4*>(dst)[i] = o;
}

// ---------------- GEMM: D[m][n] = sum_k A[m][k]*Bm[n][k] + bias ----------------
// 128x128 tile, BK=64, 256 threads = 4 waves (2x2), each wave 64x64 (4x4 MFMA tiles).
// LDS XOR-swizzled (granule g of row r stored at slot r*8 + (g ^ (r&7))): enables
// global_load_lds wave-uniform dest AND phase-balanced ds_read_b128.
#define MODE_HEAD 0   // row=token, col=channel -> bf16 [B,H,T,HD], (val+bias[n])*scale
#define MODE_CT   1   // row=channel, col=token -> bf16 [B,H,HD,T], val+bias[m] (bias per ROW)
#define MODE_OUT  2   // row=token, col=channel -> fp32 [8192,1024], val+bias[n]

template<int MODE>
__global__ __launch_bounds__(256) void gemm128(
    const unsigned short* __restrict__ A,
    const unsigned short* __restrict__ Bm,
    const float* __restrict__ bias,
    void* __restrict__ out, float scale)
{
    __shared__ unsigned short lA[128*64];
    __shared__ unsigned short lB[128*64];
    const int tid = threadIdx.x;
    const int lane = tid & 63;
    const int wave = tid >> 6;
    const int lane15 = lane & 15;
    const int quad = lane >> 4;
    const int wm = wave >> 1, wn = wave & 1;
    const int m0 = blockIdx.y * 128;
    const int n0 = blockIdx.x * 128;

    floatx4 zero = {0.f, 0.f, 0.f, 0.f};
    floatx4 acc[4][4];
    #pragma unroll
    for (int i = 0; i < 4; i++)
        #pragma unroll
        for (int j = 0; j < 4; j++) acc[i][j] = zero;

    // staging map: chunk = t*4 + wave; slot s = chunk*64 + lane; row = s>>3; g = (s&7)^(row&7)
    int srow[4], sg[4];
    #pragma unroll
    for (int t = 0; t < 4; t++){
        int s = (t*4 + wave)*64 + lane;
        srow[t] = s >> 3;
        sg[t] = (s & 7) ^ ((s >> 3) & 7);
    }

    for (int k0 = 0; k0 < 1024; k0 += 64){
        #pragma unroll
        for (int t = 0; t < 4; t++){
            int chunk = t*4 + wave;
            ld_g2l16(A  + (size_t)(m0 + srow[t])*1024 + k0 + sg[t]*8, &lA[chunk*512]);
            ld_g2l16(Bm + (size_t)(n0 + srow[t])*1024 + k0 + sg[t]*8, &lB[chunk*512]);
        }
        __syncthreads();
        #pragma unroll
        for (int ks = 0; ks < 2; ks++){
            short8 af[4], bf[4];
            #pragma unroll
            for (int i = 0; i < 4; i++){
                int ra = wm*64 + i*16 + lane15;
                int ga = (ks*4 + quad) ^ (ra & 7);
                af[i] = *reinterpret_cast<const short8*>(&lA[ra*64 + ga*8]);
                int rb = wn*64 + i*16 + lane15;
                int gb = (ks*4 + quad) ^ (rb & 7);
                bf[i] = *reinterpret_cast<const short8*>(&lB[rb*64 + gb*8]);
            }
            #pragma unroll
            for (int i = 0; i < 4; i++)
                #pragma unroll
                for (int j = 0; j < 4; j++)
                    acc[i][j] = __builtin_amdgcn_mfma_f32_16x16x32_bf16(af[i], bf[j], acc[i][j], 0, 0, 0);
        }
        __syncthreads();
    }

    // epilogue: C/D layout col = lane&15, row = quad*4 + reg
    #pragma unroll
    for (int i = 0; i < 4; i++){
        #pragma unroll
        for (int j = 0; j < 4; j++){
            if (MODE == MODE_CT){
                int n = n0 + wn*64 + j*16 + lane15;      // token
                float4 bv = *reinterpret_cast<const float4*>(&bias[m0 + wm*64 + i*16 + quad*4]);
                int b = n >> 11, t = n & 2047;
                #pragma unroll
                for (int r = 0; r < 4; r++){
                    int mm = m0 + wm*64 + i*16 + quad*4 + r;  // channel
                    float val = acc[i][j][r] + (&bv.x)[r];
                    int h = mm >> 6, d = mm & 63;
                    reinterpret_cast<unsigned short*>(out)[(((size_t)(b*16 + h))*64 + d)*2048 + t] = f2bf(val);
                }
            } else {
                int n = n0 + wn*64 + j*16 + lane15;      // channel (HEAD/OUT)
                float bv = bias[n];
                #pragma unroll
                for (int r = 0; r < 4; r++){
                    int m = m0 + wm*64 + i*16 + quad*4 + r;  // token
                    float val = (acc[i][j][r] + bv) * scale;
                    if (MODE == MODE_OUT){
                        reinterpret_cast<float*>(out)[(size_t)m*1024 + n] = val;
                    } else {
                        int b = m >> 11, t = m & 2047;
                        int h = n >> 6,  d = n & 63;
                        reinterpret_cast<unsigned short*>(out)[(((size_t)b*16 + h)*2048 + t)*64 + d] = f2bf(val);
                    }
                }
            }
        }
    }
}

// ---------------- Flash attention ----------------
// grid: (32 q-tiles, 64 bh). block 256 = 4 waves; wave w handles 16 q rows.
// q pre-scaled by 1/sqrt(64). k: [B,H,T,64] bf16. vT: [B,H,64,T] bf16.
// Register-prefetch of next K/V tile overlaps global latency with compute.
__global__ __launch_bounds__(256) void flash_attn(
    const unsigned short* __restrict__ q,
    const unsigned short* __restrict__ k,
    const unsigned short* __restrict__ vT,
    unsigned short* __restrict__ y)
{
    __shared__ unsigned short lK[64*72];
    __shared__ unsigned short lV[64*72];
    __shared__ unsigned short lP[4*16*72];
    const int tid = threadIdx.x;
    const int lane = tid & 63;
    const int wave = tid >> 6;
    const int lane15 = lane & 15;
    const int quad = lane >> 4;
    const int bh = blockIdx.y;
    const int qt = (int)gridDim.x - 1 - (int)blockIdx.x;  // longest blocks dispatch first
    const int r0 = qt*64 + wave*16;                       // global q-row base for this wave
    const int nIter = qt + 1;

    short8 qf[2];
    #pragma unroll
    for (int f = 0; f < 2; f++)
        qf[f] = *reinterpret_cast<const short8*>(q + ((size_t)bh*2048 + r0 + lane15)*64 + f*32 + quad*8);

    floatx4 zero = {0.f, 0.f, 0.f, 0.f};
    floatx4 acc[4];
    acc[0] = zero; acc[1] = zero; acc[2] = zero; acc[3] = zero;
    float m_i[4], l_i[4];
    #pragma unroll
    for (int r = 0; r < 4; r++){ m_i[r] = -INFINITY; l_i[r] = 0.f; }

    unsigned short* pw = &lP[wave*16*72];

    // staging map + prefetch of tile 0
    int srow[2], sgrp[2];
    uint4 pk[2], pv[2];
    #pragma unroll
    for (int i = 0; i < 2; i++){
        int c = i*256 + tid;
        srow[i] = c >> 3; sgrp[i] = c & 7;
        pk[i] = *reinterpret_cast<const uint4*>(k  + ((size_t)bh*2048 + srow[i])*64 + sgrp[i]*8);
        pv[i] = *reinterpret_cast<const uint4*>(vT + ((size_t)bh*64 + srow[i])*2048 + sgrp[i]*8);
    }

    for (int it = 0; it < nIter; it++){
        const int j0 = it*64;
        #pragma unroll
        for (int i = 0; i < 2; i++){
            *reinterpret_cast<uint4*>(&lK[srow[i]*72 + sgrp[i]*8]) = pk[i];
            *reinterpret_cast<uint4*>(&lV[srow[i]*72 + sgrp[i]*8]) = pv[i];
        }
        __syncthreads();

        if (it + 1 < nIter){
            int j1 = j0 + 64;
            #pragma unroll
            for (int i = 0; i < 2; i++){
                pk[i] = *reinterpret_cast<const uint4*>(k  + ((size_t)bh*2048 + j1 + srow[i])*64 + sgrp[i]*8);
                pv[i] = *reinterpret_cast<const uint4*>(vT + ((size_t)bh*64 + srow[i])*2048 + j1 + sgrp[i]*8);
            }
        }

        // S = Q K^T for 16 rows x 64 cols
        floatx4 s[4];
        #pragma unroll
        for (int tj = 0; tj < 4; tj++){
            short8 kf0 = *reinterpret_cast<const short8*>(&lK[(tj*16+lane15)*72 +      quad*8]);
            short8 kf1 = *reinterpret_cast<const short8*>(&lK[(tj*16+lane15)*72 + 32 + quad*8]);
            floatx4 z = zero;
            z = __builtin_amdgcn_mfma_f32_16x16x32_bf16(qf[0], kf0, z, 0, 0, 0);
            z = __builtin_amdgcn_mfma_f32_16x16x32_bf16(qf[1], kf1, z, 0, 0, 0);
            s[tj] = z;
        }

        // mask: col%25==24 always; causal only on the final (diagonal) iteration
        if (it == nIter - 1){
            #pragma unroll
            for (int tj = 0; tj < 4; tj++){
                int col = j0 + tj*16 + lane15;
                bool colBad = ((unsigned)col % 25u) == 24u;
                #pragma unroll
                for (int r = 0; r < 4; r++){
                    int rowq = r0 + quad*4 + r;
                    if (colBad || col > rowq) s[tj][r] = -INFINITY;
                }
            }
        } else {
            #pragma unroll
            for (int tj = 0; tj < 4; tj++){
                int col = j0 + tj*16 + lane15;
                if (((unsigned)col % 25u) == 24u){
                    #pragma unroll
                    for (int r = 0; r < 4; r++) s[tj][r] = -INFINITY;
                }
            }
        }

        // online softmax (rows live across the 16 lanes sharing quad)
        float alpha[4];
        #pragma unroll
        for (int r = 0; r < 4; r++){
            float m = fmaxf(fmaxf(s[0][r], s[1][r]), fmaxf(s[2][r], s[3][r]));
            #pragma unroll
            for (int off = 1; off < 16; off <<= 1) m = fmaxf(m, __shfl_xor(m, off));
            float mnew = fmaxf(m_i[r], m);
            alpha[r] = __expf(m_i[r] - mnew);
            m_i[r] = mnew;
            float ls = 0.f;
            #pragma unroll
            for (int tj = 0; tj < 4; tj++){
                float p = __expf(s[tj][r] - mnew);
                s[tj][r] = p;
                ls += p;
            }
            #pragma unroll
            for (int off = 1; off < 16; off <<= 1) ls += __shfl_xor(ls, off);
            l_i[r] = l_i[r]*alpha[r] + ls;
            #pragma unroll
            for (int dt = 0; dt < 4; dt++) acc[dt][r] *= alpha[r];
        }

        // P: C-layout -> per-wave LDS region -> A-layout (in-wave, no barrier needed)
        #pragma unroll
        for (int tj = 0; tj < 4; tj++)
            #pragma unroll
            for (int r = 0; r < 4; r++)
                pw[(quad*4+r)*72 + tj*16 + lane15] = f2bf(s[tj][r]);

        // O += P V   (B-operand from vT tile: rows are d, k is j contiguous)
        #pragma unroll
        for (int ks = 0; ks < 2; ks++){
            short8 pf = *reinterpret_cast<const short8*>(&pw[lane15*72 + ks*32 + quad*8]);
            #pragma unroll
            for (int dt = 0; dt < 4; dt++){
                short8 vf = *reinterpret_cast<const short8*>(&lV[(dt*16+lane15)*72 + ks*32 + quad*8]);
                acc[dt] = __builtin_amdgcn_mfma_f32_16x16x32_bf16(pf, vf, acc[dt], 0, 0, 0);
            }
        }
        __syncthreads();
    }

    const int b = bh >> 4, h = bh & 15;
    #pragma unroll
    for (int dt = 0; dt < 4; dt++){
        #pragma unroll
        for (int r = 0; r < 4; r++){
            float o = acc[dt][r] / l_i[r];
            int t = r0 + quad*4 + r;
            int cc = h*64 + dt*16 + lane15;
            y[((size_t)b*2048 + t)*1024 + cc] = f2bf(o);
        }
    }
}

// ---------------- launch ----------------
extern "C" void kernel_launch(void* const* d_in, const int* in_sizes, int n_in,
                              void* d_out, int out_size, void* d_ws, size_t ws_size,
                              hipStream_t stream)
{
    const float* x  = (const float*)d_in[0];
    const float* Wq = (const float*)d_in[1];
    const float* bq = (const float*)d_in[2];
    const float* Wk = (const float*)d_in[3];
    const float* bk = (const float*)d_in[4];
    const float* Wv = (const float*)d_in[5];
    const float* bv = (const float*)d_in[6];
    const float* Wp = (const float*)d_in[7];
    const float* bp = (const float*)d_in[8];
    float* out = (float*)d_out;

    unsigned short* ws  = (unsigned short*)d_ws;
    unsigned short* xbf = ws;                       // 8192*1024
    unsigned short* wqb = xbf + (size_t)8192*1024;  // 1024*1024 each
    unsigned short* wkb = wqb + (size_t)1024*1024;
    unsigned short* wvb = wkb + (size_t)1024*1024;
    unsigned short* wpb = wvb + (size_t)1024*1024;
    unsigned short* qws = wpb + (size_t)1024*1024;  // [B,H,T,64]
    unsigned short* kws = qws + (size_t)8388608;    // [B,H,T,64]
    unsigned short* vtw = kws + (size_t)8388608;    // [B,H,64,T]
    unsigned short* yws = vtw + (size_t)8388608;    // [B,T,C]

    cvt_kernel<<<8192, 256, 0, stream>>>(x, xbf, 2097152);
    cvt4_kernel<<<4096, 256, 0, stream>>>(Wq, Wk, Wv, Wp, wqb, wkb, wvb, wpb);

    // q,k: [8192 tok] x [1024 ch]; v: transposed output via swapped operands
    gemm128<MODE_HEAD><<<dim3(8, 64), 256, 0, stream>>>(xbf, wqb, bq, qws, 0.125f);
    gemm128<MODE_HEAD><<<dim3(8, 64), 256, 0, stream>>>(xbf, wkb, bk, kws, 1.0f);
    gemm128<MODE_CT  ><<<dim3(64, 8), 256, 0, stream>>>(wvb, xbf, bv, vtw, 1.0f);

    flash_attn<<<dim3(32, 64), 256, 0, stream>>>(qws, kws, vtw, yws);

    gemm128<MODE_OUT ><<<dim3(8, 64), 256, 0, stream>>>(yws, wpb, bp, out, 1.0f);
}